// Round 1
// baseline (21612.125 us; speedup 1.0000x reference)
//
#include <hip/hip_runtime.h>
#include <math.h>

#define V 50257
#define B 2
#define T 2048
#define D 768
#define H 12
#define HD 64
#define L 4
#define D3 (3*D)
#define D4 (4*D)
#define NTOK (B*T)          // 4096
#define EPS 1e-5f

// ---------------- embedding: x = wte[idx] + wpe[t] ----------------
__global__ __launch_bounds__(256) void embed_kernel(const int* __restrict__ idx,
                                                    const float* __restrict__ wte,
                                                    const float* __restrict__ wpe,
                                                    float* __restrict__ x) {
    int i = blockIdx.x * 256 + threadIdx.x;          // over NTOK*D
    if (i >= NTOK * D) return;
    int pos = i / D;          // b*T + t
    int d   = i - pos * D;
    int t   = pos & (T - 1);
    int tok = idx[pos];
    x[i] = wte[tok * D + d] + wpe[t * D + d];
}

// ---------------- layernorm over D=768, one block per row ----------------
// src row = blockIdx.x * src_mul + src_off ; dst row = blockIdx.x
__global__ __launch_bounds__(256) void ln_kernel(const float* __restrict__ X,
                                                 const float* __restrict__ w,
                                                 const float* __restrict__ b,
                                                 float* __restrict__ Y,
                                                 int src_mul, int src_off) {
    int srow = blockIdx.x * src_mul + src_off;
    const float* xr = X + (size_t)srow * D;
    float v[3];
    float s = 0.f, s2 = 0.f;
    #pragma unroll
    for (int j = 0; j < 3; ++j) {
        v[j] = xr[threadIdx.x + 256 * j];
        s += v[j];
        s2 += v[j] * v[j];
    }
    #pragma unroll
    for (int off = 32; off; off >>= 1) {
        s  += __shfl_xor(s, off);
        s2 += __shfl_xor(s2, off);
    }
    __shared__ float ss[4], ss2[4];
    int wave = threadIdx.x >> 6, lane = threadIdx.x & 63;
    if (lane == 0) { ss[wave] = s; ss2[wave] = s2; }
    __syncthreads();
    s  = ss[0] + ss[1] + ss[2] + ss[3];
    s2 = ss2[0] + ss2[1] + ss2[2] + ss2[3];
    float mu  = s * (1.f / D);
    float var = s2 * (1.f / D) - mu * mu;
    float rs  = rsqrtf(var + EPS);
    float* yr = Y + (size_t)blockIdx.x * D;
    #pragma unroll
    for (int j = 0; j < 3; ++j) {
        int c = threadIdx.x + 256 * j;
        yr[c] = (v[j] - mu) * rs * w[c] + b[c];
    }
}

// ---------------- generic tiled fp32 GEMM: C = act(A@W + bias) [+ residual] ----
// A[M,K] row-major, W[K,N] row-major. BM=BN=64, BK=16, 256 thr, 4x4/thread.
__global__ __launch_bounds__(256) void gemm_kernel(const float* __restrict__ A,
                                                   const float* __restrict__ W,
                                                   const float* __restrict__ bias,
                                                   const float* __restrict__ residual,
                                                   float* __restrict__ C,
                                                   int M, int N, int K, int do_gelu) {
    __shared__ float As[16][65];
    __shared__ float Ws[16][65];
    const int row0 = blockIdx.y * 64;
    const int col0 = blockIdx.x * 64;
    const int tid = threadIdx.x;
    const int tx = tid & 15;   // col group
    const int ty = tid >> 4;   // row group
    float acc[4][4] = {};
    for (int k0 = 0; k0 < K; k0 += 16) {
        // A tile: 64 rows x 16 k
        #pragma unroll
        for (int i = tid; i < 64 * 16; i += 256) {
            int m = i >> 4, kk = i & 15;
            As[kk][m] = A[(size_t)(row0 + m) * K + (k0 + kk)];
        }
        // W tile: 16 k x 64 cols
        #pragma unroll
        for (int i = tid; i < 16 * 64; i += 256) {
            int kk = i >> 6, n = i & 63;
            Ws[kk][n] = W[(size_t)(k0 + kk) * N + (col0 + n)];
        }
        __syncthreads();
        #pragma unroll
        for (int kk = 0; kk < 16; ++kk) {
            float a[4], w[4];
            #pragma unroll
            for (int i = 0; i < 4; ++i) a[i] = As[kk][ty * 4 + i];
            #pragma unroll
            for (int j = 0; j < 4; ++j) w[j] = Ws[kk][tx * 4 + j];
            #pragma unroll
            for (int i = 0; i < 4; ++i)
                #pragma unroll
                for (int j = 0; j < 4; ++j)
                    acc[i][j] = fmaf(a[i], w[j], acc[i][j]);
        }
        __syncthreads();
    }
    #pragma unroll
    for (int i = 0; i < 4; ++i) {
        int r = row0 + ty * 4 + i;
        #pragma unroll
        for (int j = 0; j < 4; ++j) {
            int c = col0 + tx * 4 + j;
            float vv = acc[i][j] + bias[c];
            if (do_gelu) vv = 0.5f * vv * (1.f + erff(vv * 0.70710678118f));
            if (residual) vv += residual[(size_t)r * N + c];
            C[(size_t)r * N + c] = vv;
        }
    }
}

// ---------------- fused causal attention, one wave per q row ----------------
// qkv layout: [NTOK, 3D]; q at col h*64, k at D + h*64, v at 2D + h*64
__global__ __launch_bounds__(256) void attn_kernel(const float* __restrict__ qkv,
                                                   float* __restrict__ y) {
    int wave = threadIdx.x >> 6;
    int lane = threadIdx.x & 63;
    int r = blockIdx.x * 4 + wave;          // 0 .. B*H*T-1
    int b = r / (H * T);
    int rem = r - b * (H * T);
    int h = rem / T;
    int q = rem - h * T;
    const float scale = 0.125f;             // 1/sqrt(64)
    const float* qrow = qkv + (size_t)(b * T + q) * D3 + h * HD;
    float qv = qrow[lane];
    float m = -INFINITY, l = 0.f, acc = 0.f;
    const float* kbase = qkv + (size_t)(b * T) * D3 + D + h * HD + lane;
    const float* vbase = qkv + (size_t)(b * T) * D3 + 2 * D + h * HD + lane;
    for (int k = 0; k <= q; ++k) {
        float kv = kbase[(size_t)k * D3];
        float vv = vbase[(size_t)k * D3];
        float s = qv * kv;
        #pragma unroll
        for (int off = 32; off; off >>= 1) s += __shfl_xor(s, off);
        s *= scale;
        float m_new = fmaxf(m, s);
        float f = expf(m - m_new);
        float p = expf(s - m_new);
        l = l * f + p;
        acc = acc * f + p * vv;
        m = m_new;
    }
    y[(size_t)(b * T + q) * D + h * HD + lane] = acc / l;
}

// ---------------- lm head: out[b,v] = dot(xf[b,:], wte[v,:]) --------------
__global__ __launch_bounds__(256) void logits_kernel(const float* __restrict__ xf,
                                                     const float* __restrict__ wte,
                                                     float* __restrict__ out) {
    int wave = threadIdx.x >> 6;
    int lane = threadIdx.x & 63;
    int gid = blockIdx.x * 4 + wave;
    if (gid >= B * V) return;
    int b = gid / V;
    int v = gid - b * V;
    const float* wr = wte + (size_t)v * D;
    const float* xr = xf + b * D;
    float s = 0.f;
    #pragma unroll
    for (int j = 0; j < 12; ++j)
        s = fmaf(wr[lane + 64 * j], xr[lane + 64 * j], s);
    #pragma unroll
    for (int off = 32; off; off >>= 1) s += __shfl_xor(s, off);
    if (lane == 0) out[gid] = s;
}

extern "C" void kernel_launch(void* const* d_in, const int* in_sizes, int n_in,
                              void* d_out, int out_size, void* d_ws, size_t ws_size,
                              hipStream_t stream) {
    const int*   idx    = (const int*)  d_in[0];
    const float* wte    = (const float*)d_in[1];
    const float* wpe    = (const float*)d_in[2];
    const float* ln1_w  = (const float*)d_in[3];
    const float* ln1_b  = (const float*)d_in[4];
    const float* attn_w = (const float*)d_in[5];
    const float* attn_b = (const float*)d_in[6];
    const float* proj_w = (const float*)d_in[7];
    const float* proj_b = (const float*)d_in[8];
    const float* ln2_w  = (const float*)d_in[9];
    const float* ln2_b  = (const float*)d_in[10];
    const float* fc_w   = (const float*)d_in[11];
    const float* fc_b   = (const float*)d_in[12];
    const float* fcp_w  = (const float*)d_in[13];
    const float* fcp_b  = (const float*)d_in[14];
    const float* lnf_w  = (const float*)d_in[15];
    const float* lnf_b  = (const float*)d_in[16];
    float* out = (float*)d_out;

    const size_t NX = (size_t)NTOK * D;        // 3145728
    float* x   = (float*)d_ws;                 // [NTOK, D]
    float* h   = x + NX;                       // [NTOK, D]
    float* y   = h + NX;                       // [NTOK, D]
    float* big = y + NX;                       // [NTOK, 4D] (also holds qkv [NTOK,3D])
    float* xf  = big + (size_t)NTOK * D4;      // [B, D]

    // embed
    embed_kernel<<<(NTOK * D + 255) / 256, 256, 0, stream>>>(idx, wte, wpe, x);

    for (int l = 0; l < L; ++l) {
        const float* l1w = ln1_w + l * D;
        const float* l1b = ln1_b + l * D;
        const float* aw  = attn_w + (size_t)l * D * D3;
        const float* ab  = attn_b + l * D3;
        const float* pw  = proj_w + (size_t)l * D * D;
        const float* pb  = proj_b + l * D;
        const float* l2w = ln2_w + l * D;
        const float* l2b = ln2_b + l * D;
        const float* fw  = fc_w + (size_t)l * D * D4;
        const float* fb  = fc_b + l * D4;
        const float* fpw = fcp_w + (size_t)l * D4 * D;
        const float* fpb = fcp_b + l * D;

        // h = ln1(x)
        ln_kernel<<<NTOK, 256, 0, stream>>>(x, l1w, l1b, h, 1, 0);
        // qkv = h @ aw + ab   -> big
        gemm_kernel<<<dim3(D3 / 64, NTOK / 64), 256, 0, stream>>>(h, aw, ab, nullptr, big,
                                                                  NTOK, D3, D, 0);
        // y = attention(qkv)
        attn_kernel<<<(B * H * T) / 4, 256, 0, stream>>>(big, y);
        // x = x + y @ pw + pb
        gemm_kernel<<<dim3(D / 64, NTOK / 64), 256, 0, stream>>>(y, pw, pb, x, x,
                                                                 NTOK, D, D, 0);
        // h = ln2(x)
        ln_kernel<<<NTOK, 256, 0, stream>>>(x, l2w, l2b, h, 1, 0);
        // big = gelu(h @ fw + fb)
        gemm_kernel<<<dim3(D4 / 64, NTOK / 64), 256, 0, stream>>>(h, fw, fb, nullptr, big,
                                                                  NTOK, D4, D, 1);
        // x = x + big @ fpw + fpb
        gemm_kernel<<<dim3(D / 64, NTOK / 64), 256, 0, stream>>>(big, fpw, fpb, x, x,
                                                                 NTOK, D, D4, 0);
    }

    // xf[b] = lnf(x[b*T + T-1])
    ln_kernel<<<B, 256, 0, stream>>>(x, lnf_w, lnf_b, xf, T, T - 1);
    // out[b,v] = xf[b] . wte[v]
    logits_kernel<<<(B * V + 3) / 4, 256, 0, stream>>>(xf, wte, out);
}

// Round 2
// 9656.055 us; speedup vs baseline: 2.2382x; 2.2382x over previous
//
#include <hip/hip_runtime.h>
#include <math.h>

#define V 50257
#define B 2
#define T 2048
#define D 768
#define H 12
#define HD 64
#define L 4
#define D3 (3*D)
#define D4 (4*D)
#define NTOK (B*T)          // 4096
#define EPS 1e-5f

// ---------------- embedding: x = wte[idx] + wpe[t] ----------------
__global__ __launch_bounds__(256) void embed_kernel(const int* __restrict__ idx,
                                                    const float* __restrict__ wte,
                                                    const float* __restrict__ wpe,
                                                    float* __restrict__ x) {
    int i = blockIdx.x * 256 + threadIdx.x;          // over NTOK*D
    if (i >= NTOK * D) return;
    int pos = i / D;          // b*T + t
    int d   = i - pos * D;
    int t   = pos & (T - 1);
    int tok = idx[pos];
    x[i] = wte[tok * D + d] + wpe[t * D + d];
}

// ---------------- layernorm over D=768, one block per row ----------------
// src row = blockIdx.x * src_mul + src_off ; dst row = blockIdx.x
__global__ __launch_bounds__(256) void ln_kernel(const float* __restrict__ X,
                                                 const float* __restrict__ w,
                                                 const float* __restrict__ b,
                                                 float* __restrict__ Y,
                                                 int src_mul, int src_off) {
    int srow = blockIdx.x * src_mul + src_off;
    const float* xr = X + (size_t)srow * D;
    float v[3];
    float s = 0.f, s2 = 0.f;
    #pragma unroll
    for (int j = 0; j < 3; ++j) {
        v[j] = xr[threadIdx.x + 256 * j];
        s += v[j];
        s2 += v[j] * v[j];
    }
    #pragma unroll
    for (int off = 32; off; off >>= 1) {
        s  += __shfl_xor(s, off);
        s2 += __shfl_xor(s2, off);
    }
    __shared__ float ss[4], ss2[4];
    int wave = threadIdx.x >> 6, lane = threadIdx.x & 63;
    if (lane == 0) { ss[wave] = s; ss2[wave] = s2; }
    __syncthreads();
    s  = ss[0] + ss[1] + ss[2] + ss[3];
    s2 = ss2[0] + ss2[1] + ss2[2] + ss2[3];
    float mu  = s * (1.f / D);
    float var = s2 * (1.f / D) - mu * mu;
    float rs  = rsqrtf(var + EPS);
    float* yr = Y + (size_t)blockIdx.x * D;
    #pragma unroll
    for (int j = 0; j < 3; ++j) {
        int c = threadIdx.x + 256 * j;
        yr[c] = (v[j] - mu) * rs * w[c] + b[c];
    }
}

// ---------------- generic tiled fp32 GEMM: C = act(A@W + bias) [+ residual] ----
// A[M,K] row-major, W[K,N] row-major. BM=BN=64, BK=16, 256 thr, 4x4/thread.
__global__ __launch_bounds__(256) void gemm_kernel(const float* __restrict__ A,
                                                   const float* __restrict__ W,
                                                   const float* __restrict__ bias,
                                                   const float* __restrict__ residual,
                                                   float* __restrict__ C,
                                                   int M, int N, int K, int do_gelu) {
    __shared__ float As[16][65];
    __shared__ float Ws[16][65];
    const int row0 = blockIdx.y * 64;
    const int col0 = blockIdx.x * 64;
    const int tid = threadIdx.x;
    const int tx = tid & 15;   // col group
    const int ty = tid >> 4;   // row group
    float acc[4][4] = {};
    for (int k0 = 0; k0 < K; k0 += 16) {
        // A tile: 64 rows x 16 k
        #pragma unroll
        for (int i = tid; i < 64 * 16; i += 256) {
            int m = i >> 4, kk = i & 15;
            As[kk][m] = A[(size_t)(row0 + m) * K + (k0 + kk)];
        }
        // W tile: 16 k x 64 cols
        #pragma unroll
        for (int i = tid; i < 16 * 64; i += 256) {
            int kk = i >> 6, n = i & 63;
            Ws[kk][n] = W[(size_t)(k0 + kk) * N + (col0 + n)];
        }
        __syncthreads();
        #pragma unroll
        for (int kk = 0; kk < 16; ++kk) {
            float a[4], w[4];
            #pragma unroll
            for (int i = 0; i < 4; ++i) a[i] = As[kk][ty * 4 + i];
            #pragma unroll
            for (int j = 0; j < 4; ++j) w[j] = Ws[kk][tx * 4 + j];
            #pragma unroll
            for (int i = 0; i < 4; ++i)
                #pragma unroll
                for (int j = 0; j < 4; ++j)
                    acc[i][j] = fmaf(a[i], w[j], acc[i][j]);
        }
        __syncthreads();
    }
    #pragma unroll
    for (int i = 0; i < 4; ++i) {
        int r = row0 + ty * 4 + i;
        #pragma unroll
        for (int j = 0; j < 4; ++j) {
            int c = col0 + tx * 4 + j;
            float vv = acc[i][j] + bias[c];
            if (do_gelu) vv = 0.5f * vv * (1.f + erff(vv * 0.70710678118f));
            if (residual) vv += residual[(size_t)r * N + c];
            C[(size_t)r * N + c] = vv;
        }
    }
}

// ---------------- tiled flash attention ----------------
// One block = 4 consecutive q rows of one (b,h); wave w owns q = q0+w.
// K-tiles of 64 keys staged in LDS: Kt[d][j] (transposed, pad 65) and
// Vs[j][d] (natural, pad 65). Lane j computes score for key j (QK reads
// stride-1 in Kt); lane d accumulates output dim d (PV reads stride-1 in Vs).
__global__ __launch_bounds__(256) void attn_kernel(const float* __restrict__ qkv,
                                                   float* __restrict__ y) {
    __shared__ float Kt[64][65];
    __shared__ float Vs[64][65];
    __shared__ float Ps[4][64];
    __shared__ float Qs[4][64];

    const int tid  = threadIdx.x;
    const int w    = tid >> 6;
    const int lane = tid & 63;
    const int bh   = blockIdx.x / (T / 4);
    const int q0   = (blockIdx.x % (T / 4)) * 4;
    const int b    = bh / H;
    const int h    = bh - b * H;
    const int q    = q0 + w;
    const float scale = 0.125f;             // 1/sqrt(64)

    const float* base = qkv + (size_t)(b * T) * D3 + h * HD;   // +row*D3 +{0,D,2D}+d
    // q row into LDS (wave-coherent, no barrier needed before own-wave read)
    Qs[w][lane] = base[(size_t)q * D3 + lane];

    float acc = 0.f, m = -INFINITY, l = 0.f;
    const int nt = ((q0 + 3) >> 6) + 1;     // tiles cover keys 0..q0+3

    for (int kt = 0; kt < nt; ++kt) {
        const int k0 = kt * 64;
        // cooperative tile load: each wave stages 16 keys of K and V
        #pragma unroll
        for (int i = 0; i < 16; ++i) {
            int j = w * 16 + i;
            size_t g = (size_t)(k0 + j) * D3 + lane;
            Kt[lane][j] = base[g + D];       // LDS write bank-free (2-way)
            Vs[j][lane] = base[g + 2 * D];   // stride-1 write
        }
        __syncthreads();

        // scores: lane j = key k0+j
        float s = 0.f;
        #pragma unroll
        for (int d = 0; d < 64; ++d)
            s = fmaf(Qs[w][d], Kt[d][lane], s);
        s *= scale;
        if (k0 + lane > q) s = -INFINITY;

        // online softmax across the wave's 64 scores
        float mt = s;
        #pragma unroll
        for (int off = 32; off; off >>= 1) mt = fmaxf(mt, __shfl_xor(mt, off));
        float m_new = fmaxf(m, mt);
        float alpha = __expf(m - m_new);     // wave-uniform
        float p = __expf(s - m_new);         // 0 for masked lanes
        float ps = p;
        #pragma unroll
        for (int off = 32; off; off >>= 1) ps += __shfl_xor(ps, off);
        l = l * alpha + ps;
        Ps[w][lane] = p;                     // wave-coherent

        // PV: lane d accumulates output dim d
        float a2 = 0.f;
        #pragma unroll
        for (int j = 0; j < 64; ++j)
            a2 = fmaf(Ps[w][j], Vs[j][lane], a2);
        acc = acc * alpha + a2;
        m = m_new;
        __syncthreads();
    }

    y[(size_t)(b * T + q) * D + h * HD + lane] = acc / l;
}

// ---------------- lm head: out[b,v] = dot(xf[b,:], wte[v,:]) --------------
__global__ __launch_bounds__(256) void logits_kernel(const float* __restrict__ xf,
                                                     const float* __restrict__ wte,
                                                     float* __restrict__ out) {
    int wave = threadIdx.x >> 6;
    int lane = threadIdx.x & 63;
    int gid = blockIdx.x * 4 + wave;
    if (gid >= B * V) return;
    int b = gid / V;
    int v = gid - b * V;
    const float* wr = wte + (size_t)v * D;
    const float* xr = xf + b * D;
    float s = 0.f;
    #pragma unroll
    for (int j = 0; j < 12; ++j)
        s = fmaf(wr[lane + 64 * j], xr[lane + 64 * j], s);
    #pragma unroll
    for (int off = 32; off; off >>= 1) s += __shfl_xor(s, off);
    if (lane == 0) out[gid] = s;
}

extern "C" void kernel_launch(void* const* d_in, const int* in_sizes, int n_in,
                              void* d_out, int out_size, void* d_ws, size_t ws_size,
                              hipStream_t stream) {
    const int*   idx    = (const int*)  d_in[0];
    const float* wte    = (const float*)d_in[1];
    const float* wpe    = (const float*)d_in[2];
    const float* ln1_w  = (const float*)d_in[3];
    const float* ln1_b  = (const float*)d_in[4];
    const float* attn_w = (const float*)d_in[5];
    const float* attn_b = (const float*)d_in[6];
    const float* proj_w = (const float*)d_in[7];
    const float* proj_b = (const float*)d_in[8];
    const float* ln2_w  = (const float*)d_in[9];
    const float* ln2_b  = (const float*)d_in[10];
    const float* fc_w   = (const float*)d_in[11];
    const float* fc_b   = (const float*)d_in[12];
    const float* fcp_w  = (const float*)d_in[13];
    const float* fcp_b  = (const float*)d_in[14];
    const float* lnf_w  = (const float*)d_in[15];
    const float* lnf_b  = (const float*)d_in[16];
    float* out = (float*)d_out;

    const size_t NX = (size_t)NTOK * D;        // 3145728
    float* x   = (float*)d_ws;                 // [NTOK, D]
    float* h   = x + NX;                       // [NTOK, D]
    float* y   = h + NX;                       // [NTOK, D]
    float* big = y + NX;                       // [NTOK, 4D] (also holds qkv [NTOK,3D])
    float* xf  = big + (size_t)NTOK * D4;      // [B, D]

    // embed
    embed_kernel<<<(NTOK * D + 255) / 256, 256, 0, stream>>>(idx, wte, wpe, x);

    for (int l = 0; l < L; ++l) {
        const float* l1w = ln1_w + l * D;
        const float* l1b = ln1_b + l * D;
        const float* aw  = attn_w + (size_t)l * D * D3;
        const float* ab  = attn_b + l * D3;
        const float* pw  = proj_w + (size_t)l * D * D;
        const float* pb  = proj_b + l * D;
        const float* l2w = ln2_w + l * D;
        const float* l2b = ln2_b + l * D;
        const float* fw  = fc_w + (size_t)l * D * D4;
        const float* fb  = fc_b + l * D4;
        const float* fpw = fcp_w + (size_t)l * D4 * D;
        const float* fpb = fcp_b + l * D;

        // h = ln1(x)
        ln_kernel<<<NTOK, 256, 0, stream>>>(x, l1w, l1b, h, 1, 0);
        // qkv = h @ aw + ab   -> big
        gemm_kernel<<<dim3(D3 / 64, NTOK / 64), 256, 0, stream>>>(h, aw, ab, nullptr, big,
                                                                  NTOK, D3, D, 0);
        // y = attention(qkv)
        attn_kernel<<<B * H * (T / 4), 256, 0, stream>>>(big, y);
        // x = x + y @ pw + pb
        gemm_kernel<<<dim3(D / 64, NTOK / 64), 256, 0, stream>>>(y, pw, pb, x, x,
                                                                 NTOK, D, D, 0);
        // h = ln2(x)
        ln_kernel<<<NTOK, 256, 0, stream>>>(x, l2w, l2b, h, 1, 0);
        // big = gelu(h @ fw + fb)
        gemm_kernel<<<dim3(D4 / 64, NTOK / 64), 256, 0, stream>>>(h, fw, fb, nullptr, big,
                                                                  NTOK, D4, D, 1);
        // x = x + big @ fpw + fpb
        gemm_kernel<<<dim3(D / 64, NTOK / 64), 256, 0, stream>>>(big, fpw, fpb, x, x,
                                                                 NTOK, D, D4, 0);
    }

    // xf[b] = lnf(x[b*T + T-1])
    ln_kernel<<<B, 256, 0, stream>>>(x, lnf_w, lnf_b, xf, T, T - 1);
    // out[b,v] = xf[b] . wte[v]
    logits_kernel<<<(B * V + 3) / 4, 256, 0, stream>>>(xf, wte, out);
}

// Round 3
// 4771.183 us; speedup vs baseline: 4.5297x; 2.0238x over previous
//
#include <hip/hip_runtime.h>
#include <math.h>

#define V 50257
#define B 2
#define T 2048
#define D 768
#define H 12
#define HD 64
#define L 4
#define D3 (3*D)
#define D4 (4*D)
#define NTOK (B*T)          // 4096
#define EPS 1e-5f

typedef __bf16 v8bf __attribute__((ext_vector_type(8)));
typedef float  v4f  __attribute__((ext_vector_type(4)));

#define GAS(p) ((const __attribute__((address_space(1))) void*)(p))
#define LAS(p) ((__attribute__((address_space(3))) void*)(p))

// ---------------- embedding: x = wte[idx] + wpe[t] (fp32) ----------------
__global__ __launch_bounds__(256) void embed_kernel(const int* __restrict__ idx,
                                                    const float* __restrict__ wte,
                                                    const float* __restrict__ wpe,
                                                    float* __restrict__ x) {
    int i = blockIdx.x * 256 + threadIdx.x;
    if (i >= NTOK * D) return;
    int pos = i / D;
    int d   = i - pos * D;
    int t   = pos & (T - 1);
    int tok = idx[pos];
    x[i] = wte[tok * D + d] + wpe[t * D + d];
}

// ---------------- layernorm: fp32 in, bf16 out ----------------
__global__ __launch_bounds__(256) void ln_kernel(const float* __restrict__ X,
                                                 const float* __restrict__ w,
                                                 const float* __restrict__ b,
                                                 __bf16* __restrict__ Y,
                                                 int src_mul, int src_off) {
    int srow = blockIdx.x * src_mul + src_off;
    const float* xr = X + (size_t)srow * D;
    float v[3];
    float s = 0.f, s2 = 0.f;
    #pragma unroll
    for (int j = 0; j < 3; ++j) {
        v[j] = xr[threadIdx.x + 256 * j];
        s += v[j];
        s2 += v[j] * v[j];
    }
    #pragma unroll
    for (int off = 32; off; off >>= 1) {
        s  += __shfl_xor(s, off);
        s2 += __shfl_xor(s2, off);
    }
    __shared__ float ss[4], ss2[4];
    int wave = threadIdx.x >> 6, lane = threadIdx.x & 63;
    if (lane == 0) { ss[wave] = s; ss2[wave] = s2; }
    __syncthreads();
    s  = ss[0] + ss[1] + ss[2] + ss[3];
    s2 = ss2[0] + ss2[1] + ss2[2] + ss2[3];
    float mu  = s * (1.f / D);
    float var = s2 * (1.f / D) - mu * mu;
    float rs  = rsqrtf(var + EPS);
    __bf16* yr = Y + (size_t)blockIdx.x * D;
    #pragma unroll
    for (int j = 0; j < 3; ++j) {
        int c = threadIdx.x + 256 * j;
        yr[c] = (__bf16)((v[j] - mu) * rs * w[c] + b[c]);
    }
}

// ---------------- weight convert+transpose: W[K][N] fp32 -> Wt[N][K] bf16 ----
__global__ __launch_bounds__(256) void convw_kernel(const float* __restrict__ W,
                                                    __bf16* __restrict__ Wt,
                                                    int K, int N) {
    __shared__ float t[32][33];
    const int n0 = blockIdx.x * 32, k0 = blockIdx.y * 32;
    const int tx = threadIdx.x & 31, ty = threadIdx.x >> 5;   // ty 0..7
    #pragma unroll
    for (int p = 0; p < 4; ++p)
        t[ty + 8 * p][tx] = W[(size_t)(k0 + ty + 8 * p) * N + n0 + tx];
    __syncthreads();
    #pragma unroll
    for (int p = 0; p < 4; ++p)
        Wt[(size_t)(n0 + ty + 8 * p) * K + k0 + tx] = (__bf16)t[tx][ty + 8 * p];
}

// ---------------- bf16 MFMA GEMM (B^T form): C = act(A @ Wt^T + bias)[+res] ---
// A[M][K] bf16 row-major, Wt[N][K] bf16 row-major. 128x128 tile, BK=32,
// 256 thr = 4 waves in 2x2, each wave 4x4 grid of 16x16x32 MFMAs.
// LDS tiles stored in fragment-read order: for half h (rows h*64..h*64+63),
// element (row = h*64 + i*16 + mm, k = q*8 + j) lives at byte
// h*4096 + i*1024 + q*256 + mm*16 + j*2.  Wave reads frag i as 64 lanes x
// contiguous 16B (conflict-free); staging writes are wave-uniform-base +
// lane*16 (global_load_lds requirement), with the global address decoded
// from the chunk id. M, N, K all divisible by 128/128/32 here - no guards.
template<bool OUTBF16, bool DOGELU, bool DORES>
__global__ __launch_bounds__(256) void gemm_bt(const __bf16* __restrict__ A,
                                               const __bf16* __restrict__ Wt,
                                               const float* __restrict__ bias,
                                               const float* __restrict__ res,
                                               void* __restrict__ Cout,
                                               int N, int K) {
    __shared__ __align__(16) __bf16 As[4096];   // 8 KB
    __shared__ __align__(16) __bf16 Bs[4096];   // 8 KB
    const int tid  = threadIdx.x;
    const int w    = tid >> 6;
    const int lane = tid & 63;
    const int row0 = blockIdx.y * 128;
    const int col0 = blockIdx.x * 128;

    // staging decode: chunk c0 = w*64+lane (h=0); round 1 adds 256 chunks (h=1)
    const int c0   = w * 64 + lane;
    const int si   = (c0 >> 6) & 3;
    const int sq   = (c0 >> 4) & 3;
    const int sm   = c0 & 15;
    const int srow = si * 16 + sm;
    const int sk   = sq * 8;
    const __bf16* gA0 = A  + (size_t)(row0 + srow) * K + sk;
    const __bf16* gA1 = gA0 + (size_t)64 * K;
    const __bf16* gB0 = Wt + (size_t)(col0 + srow) * K + sk;
    const __bf16* gB1 = gB0 + (size_t)64 * K;
    __bf16* lA0 = As + (size_t)c0 * 8;
    __bf16* lA1 = As + (size_t)(c0 + 256) * 8;
    __bf16* lB0 = Bs + (size_t)c0 * 8;
    __bf16* lB1 = Bs + (size_t)(c0 + 256) * 8;

    const int wr = w >> 1, wc = w & 1;
    const __bf16* rA = As + wr * 2048 + lane * 8;
    const __bf16* rB = Bs + wc * 2048 + lane * 8;

    v4f acc[4][4] = {};
    for (int k0 = 0; k0 < K; k0 += 32) {
        __builtin_amdgcn_global_load_lds(GAS(gA0), LAS(lA0), 16, 0, 0);
        __builtin_amdgcn_global_load_lds(GAS(gA1), LAS(lA1), 16, 0, 0);
        __builtin_amdgcn_global_load_lds(GAS(gB0), LAS(lB0), 16, 0, 0);
        __builtin_amdgcn_global_load_lds(GAS(gB1), LAS(lB1), 16, 0, 0);
        gA0 += 32; gA1 += 32; gB0 += 32; gB1 += 32;
        __syncthreads();                 // drains vmcnt before reads
        v8bf af[4], bfr[4];
        #pragma unroll
        for (int i = 0; i < 4; ++i) af[i]  = *(const v8bf*)(rA + i * 512);
        #pragma unroll
        for (int j = 0; j < 4; ++j) bfr[j] = *(const v8bf*)(rB + j * 512);
        #pragma unroll
        for (int i = 0; i < 4; ++i)
            #pragma unroll
            for (int j = 0; j < 4; ++j)
                acc[i][j] = __builtin_amdgcn_mfma_f32_16x16x32_bf16(af[i], bfr[j], acc[i][j], 0, 0, 0);
        __syncthreads();                 // LDS reuse next iter
    }

    const int er = (lane >> 4) * 4;
    const int ec = lane & 15;
    #pragma unroll
    for (int j = 0; j < 4; ++j) {
        const int col = col0 + wc * 64 + j * 16 + ec;
        const float bval = bias[col];
        #pragma unroll
        for (int i = 0; i < 4; ++i) {
            #pragma unroll
            for (int rr = 0; rr < 4; ++rr) {
                const int row = row0 + wr * 64 + i * 16 + er + rr;
                float vv = acc[i][j][rr] + bval;
                if (DOGELU) vv = 0.5f * vv * (1.f + erff(vv * 0.70710678118f));
                if (DORES)  vv += res[(size_t)row * N + col];
                if (OUTBF16) ((__bf16*)Cout)[(size_t)row * N + col] = (__bf16)vv;
                else         ((float*) Cout)[(size_t)row * N + col] = vv;
            }
        }
    }
}

// ---------------- tiled flash attention (fp32 qkv in, bf16 y out) ----------
__global__ __launch_bounds__(256) void attn_kernel(const float* __restrict__ qkv,
                                                   __bf16* __restrict__ y) {
    __shared__ float Kt[64][65];
    __shared__ float Vs[64][65];
    __shared__ float Ps[4][64];
    __shared__ float Qs[4][64];

    const int tid  = threadIdx.x;
    const int w    = tid >> 6;
    const int lane = tid & 63;
    const int bh   = blockIdx.x / (T / 4);
    const int q0   = (blockIdx.x % (T / 4)) * 4;
    const int b    = bh / H;
    const int h    = bh - b * H;
    const int q    = q0 + w;
    const float scale = 0.125f;

    const float* base = qkv + (size_t)(b * T) * D3 + h * HD;
    Qs[w][lane] = base[(size_t)q * D3 + lane];

    float acc = 0.f, m = -INFINITY, l = 0.f;
    const int nt = ((q0 + 3) >> 6) + 1;

    for (int kt = 0; kt < nt; ++kt) {
        const int k0 = kt * 64;
        #pragma unroll
        for (int i = 0; i < 16; ++i) {
            int j = w * 16 + i;
            size_t g = (size_t)(k0 + j) * D3 + lane;
            Kt[lane][j] = base[g + D];
            Vs[j][lane] = base[g + 2 * D];
        }
        __syncthreads();

        float s = 0.f;
        #pragma unroll
        for (int d = 0; d < 64; ++d)
            s = fmaf(Qs[w][d], Kt[d][lane], s);
        s *= scale;
        if (k0 + lane > q) s = -INFINITY;

        float mt = s;
        #pragma unroll
        for (int off = 32; off; off >>= 1) mt = fmaxf(mt, __shfl_xor(mt, off));
        float m_new = fmaxf(m, mt);
        float alpha = __expf(m - m_new);
        float p = __expf(s - m_new);
        float ps = p;
        #pragma unroll
        for (int off = 32; off; off >>= 1) ps += __shfl_xor(ps, off);
        l = l * alpha + ps;
        Ps[w][lane] = p;

        float a2 = 0.f;
        #pragma unroll
        for (int j = 0; j < 64; ++j)
            a2 = fmaf(Ps[w][j], Vs[j][lane], a2);
        acc = acc * alpha + a2;
        m = m_new;
        __syncthreads();
    }

    y[(size_t)(b * T + q) * D + h * HD + lane] = (__bf16)(acc / l);
}

// ---------------- lm head: out[b,v] = dot(xf[b,:], wte[v,:]) --------------
__global__ __launch_bounds__(256) void logits_kernel(const __bf16* __restrict__ xf,
                                                     const float* __restrict__ wte,
                                                     float* __restrict__ out) {
    int wave = threadIdx.x >> 6;
    int lane = threadIdx.x & 63;
    int gid = blockIdx.x * 4 + wave;
    if (gid >= B * V) return;
    int b = gid / V;
    int v = gid - b * V;
    const float* wr = wte + (size_t)v * D;
    const __bf16* xr = xf + b * D;
    float s = 0.f;
    #pragma unroll
    for (int j = 0; j < 12; ++j)
        s = fmaf(wr[lane + 64 * j], (float)xr[lane + 64 * j], s);
    #pragma unroll
    for (int off = 32; off; off >>= 1) s += __shfl_xor(s, off);
    if (lane == 0) out[gid] = s;
}

extern "C" void kernel_launch(void* const* d_in, const int* in_sizes, int n_in,
                              void* d_out, int out_size, void* d_ws, size_t ws_size,
                              hipStream_t stream) {
    const int*   idx    = (const int*)  d_in[0];
    const float* wte    = (const float*)d_in[1];
    const float* wpe    = (const float*)d_in[2];
    const float* ln1_w  = (const float*)d_in[3];
    const float* ln1_b  = (const float*)d_in[4];
    const float* attn_w = (const float*)d_in[5];
    const float* attn_b = (const float*)d_in[6];
    const float* proj_w = (const float*)d_in[7];
    const float* proj_b = (const float*)d_in[8];
    const float* ln2_w  = (const float*)d_in[9];
    const float* ln2_b  = (const float*)d_in[10];
    const float* fc_w   = (const float*)d_in[11];
    const float* fc_b   = (const float*)d_in[12];
    const float* fcp_w  = (const float*)d_in[13];
    const float* fcp_b  = (const float*)d_in[14];
    const float* lnf_w  = (const float*)d_in[15];
    const float* lnf_b  = (const float*)d_in[16];
    float* out = (float*)d_out;

    // workspace carve (~77 MB); gelu-out (bf16) aliases qkv (fp32, dead by then)
    char* ws = (char*)d_ws;
    float*  x    = (float*)ws;  ws += (size_t)NTOK * D  * 4;   // residual stream
    float*  qkv  = (float*)ws;                                  // [NTOK,3D] fp32
    __bf16* gb   = (__bf16*)ws; ws += (size_t)NTOK * D3 * 4;   // gelu out bf16 (alias)
    __bf16* hb   = (__bf16*)ws; ws += (size_t)NTOK * D  * 2;   // ln out
    __bf16* yb   = (__bf16*)ws; ws += (size_t)NTOK * D  * 2;   // attn out
    __bf16* awt  = (__bf16*)ws; ws += (size_t)D3 * D   * 2;    // attn_w^T
    __bf16* pwt  = (__bf16*)ws; ws += (size_t)D  * D   * 2;    // proj_w^T
    __bf16* fwt  = (__bf16*)ws; ws += (size_t)D4 * D   * 2;    // fc_w^T
    __bf16* fpwt = (__bf16*)ws; ws += (size_t)D  * D4  * 2;    // fcp_w^T
    __bf16* xf   = (__bf16*)ws; ws += (size_t)B * D    * 2;

    embed_kernel<<<(NTOK * D + 255) / 256, 256, 0, stream>>>(idx, wte, wpe, x);

    for (int l = 0; l < L; ++l) {
        const float* l1w = ln1_w + l * D;
        const float* l1b = ln1_b + l * D;
        const float* aw  = attn_w + (size_t)l * D * D3;
        const float* ab  = attn_b + l * D3;
        const float* pw  = proj_w + (size_t)l * D * D;
        const float* pb  = proj_b + l * D;
        const float* l2w = ln2_w + l * D;
        const float* l2b = ln2_b + l * D;
        const float* fw  = fc_w + (size_t)l * D * D4;
        const float* fb  = fc_b + l * D4;
        const float* fpw = fcp_w + (size_t)l * D4 * D;
        const float* fpb = fcp_b + l * D;

        // convert this layer's weights to bf16 transposed
        convw_kernel<<<dim3(D3 / 32, D / 32),  256, 0, stream>>>(aw,  awt,  D,  D3);
        convw_kernel<<<dim3(D / 32,  D / 32),  256, 0, stream>>>(pw,  pwt,  D,  D);
        convw_kernel<<<dim3(D4 / 32, D / 32),  256, 0, stream>>>(fw,  fwt,  D,  D4);
        convw_kernel<<<dim3(D / 32,  D4 / 32), 256, 0, stream>>>(fpw, fpwt, D4, D);

        // h = ln1(x)  [bf16]
        ln_kernel<<<NTOK, 256, 0, stream>>>(x, l1w, l1b, hb, 1, 0);
        // qkv = h @ aw + ab  [fp32]
        gemm_bt<false, false, false><<<dim3(D3 / 128, NTOK / 128), 256, 0, stream>>>(
            hb, awt, ab, nullptr, qkv, D3, D);
        // y = attention(qkv)  [bf16]
        attn_kernel<<<B * H * (T / 4), 256, 0, stream>>>(qkv, yb);
        // x = x + y @ pw + pb  [fp32, in-place residual]
        gemm_bt<false, false, true><<<dim3(D / 128, NTOK / 128), 256, 0, stream>>>(
            yb, pwt, pb, x, x, D, D);
        // h = ln2(x)  [bf16]
        ln_kernel<<<NTOK, 256, 0, stream>>>(x, l2w, l2b, hb, 1, 0);
        // gb = gelu(h @ fw + fb)  [bf16]
        gemm_bt<true, true, false><<<dim3(D4 / 128, NTOK / 128), 256, 0, stream>>>(
            hb, fwt, fb, nullptr, gb, D4, D);
        // x = x + gb @ fpw + fpb  [fp32, in-place residual]
        gemm_bt<false, false, true><<<dim3(D / 128, NTOK / 128), 256, 0, stream>>>(
            gb, fpwt, fpb, x, x, D, D4);
    }

    // xf[b] = lnf(x[b*T + T-1])  [bf16]
    ln_kernel<<<B, 256, 0, stream>>>(x, lnf_w, lnf_b, xf, T, T - 1);
    // out[b,v] = xf[b] . wte[v]
    logits_kernel<<<(B * V + 3) / 4, 256, 0, stream>>>(xf, wte, out);
}

// Round 4
// 1640.086 us; speedup vs baseline: 13.1774x; 2.9091x over previous
//
#include <hip/hip_runtime.h>
#include <math.h>

#define V 50257
#define B 2
#define T 2048
#define D 768
#define H 12
#define HD 64
#define L 4
#define D3 (3*D)
#define D4 (4*D)
#define NTOK (B*T)          // 4096
#define EPS 1e-5f

typedef __bf16 v8bf __attribute__((ext_vector_type(8)));
typedef unsigned short v8us __attribute__((ext_vector_type(8)));
typedef float  v4f  __attribute__((ext_vector_type(4)));

#define GAS(p) ((const __attribute__((address_space(1))) void*)(p))
#define LAS(p) ((__attribute__((address_space(3))) void*)(p))

// swizzled LDS tile addressing: 64-elem (128B) rows, 16B chunks, chunk ^= row&7.
// element (row, col): idx = row*64 + ((col>>3 ^ (row&7))<<3) + (col&7)
#define LIDX(row, chunk) ((row)*64 + ((((chunk) ^ ((row)&7)))<<3))

// ---------------- embedding: x = wte[idx] + wpe[t] (fp32) ----------------
__global__ __launch_bounds__(256) void embed_kernel(const int* __restrict__ idx,
                                                    const float* __restrict__ wte,
                                                    const float* __restrict__ wpe,
                                                    float* __restrict__ x) {
    int i = blockIdx.x * 256 + threadIdx.x;
    if (i >= NTOK * D) return;
    int pos = i / D;
    int d   = i - pos * D;
    int t   = pos & (T - 1);
    int tok = idx[pos];
    x[i] = wte[tok * D + d] + wpe[t * D + d];
}

// ---------------- layernorm: fp32 in, bf16 out ----------------
__global__ __launch_bounds__(256) void ln_kernel(const float* __restrict__ X,
                                                 const float* __restrict__ w,
                                                 const float* __restrict__ b,
                                                 __bf16* __restrict__ Y,
                                                 int src_mul, int src_off) {
    int srow = blockIdx.x * src_mul + src_off;
    const float* xr = X + (size_t)srow * D;
    float v[3];
    float s = 0.f, s2 = 0.f;
    #pragma unroll
    for (int j = 0; j < 3; ++j) {
        v[j] = xr[threadIdx.x + 256 * j];
        s += v[j];
        s2 += v[j] * v[j];
    }
    #pragma unroll
    for (int off = 32; off; off >>= 1) {
        s  += __shfl_xor(s, off);
        s2 += __shfl_xor(s2, off);
    }
    __shared__ float ss[4], ss2[4];
    int wave = threadIdx.x >> 6, lane = threadIdx.x & 63;
    if (lane == 0) { ss[wave] = s; ss2[wave] = s2; }
    __syncthreads();
    s  = ss[0] + ss[1] + ss[2] + ss[3];
    s2 = ss2[0] + ss2[1] + ss2[2] + ss2[3];
    float mu  = s * (1.f / D);
    float var = s2 * (1.f / D) - mu * mu;
    float rs  = rsqrtf(var + EPS);
    __bf16* yr = Y + (size_t)blockIdx.x * D;
    #pragma unroll
    for (int j = 0; j < 3; ++j) {
        int c = threadIdx.x + 256 * j;
        yr[c] = (__bf16)((v[j] - mu) * rs * w[c] + b[c]);
    }
}

// ---------------- weight convert+transpose: W[K][N] fp32 -> Wt[N][K] bf16 ----
__global__ __launch_bounds__(256) void convw_kernel(const float* __restrict__ W,
                                                    __bf16* __restrict__ Wt,
                                                    int K, int N) {
    __shared__ float t[32][33];
    const int n0 = blockIdx.x * 32, k0 = blockIdx.y * 32;
    const int tx = threadIdx.x & 31, ty = threadIdx.x >> 5;   // ty 0..7
    #pragma unroll
    for (int p = 0; p < 4; ++p)
        t[ty + 8 * p][tx] = W[(size_t)(k0 + ty + 8 * p) * N + n0 + tx];
    __syncthreads();
    #pragma unroll
    for (int p = 0; p < 4; ++p)
        Wt[(size_t)(n0 + ty + 8 * p) * K + k0 + tx] = (__bf16)t[tx][ty + 8 * p];
}

// ---------------- bf16 MFMA GEMM (B^T form): C = act(A @ Wt^T + bias)[+res] ---
template<bool OUTBF16, bool DOGELU, bool DORES>
__global__ __launch_bounds__(256) void gemm_bt(const __bf16* __restrict__ A,
                                               const __bf16* __restrict__ Wt,
                                               const float* __restrict__ bias,
                                               const float* __restrict__ res,
                                               void* __restrict__ Cout,
                                               int N, int K) {
    __shared__ __align__(16) __bf16 As[4096];   // 8 KB
    __shared__ __align__(16) __bf16 Bs[4096];   // 8 KB
    const int tid  = threadIdx.x;
    const int w    = tid >> 6;
    const int lane = tid & 63;
    const int row0 = blockIdx.y * 128;
    const int col0 = blockIdx.x * 128;

    const int c0   = w * 64 + lane;
    const int si   = (c0 >> 6) & 3;
    const int sq   = (c0 >> 4) & 3;
    const int sm   = c0 & 15;
    const int srow = si * 16 + sm;
    const int sk   = sq * 8;
    const __bf16* gA0 = A  + (size_t)(row0 + srow) * K + sk;
    const __bf16* gA1 = gA0 + (size_t)64 * K;
    const __bf16* gB0 = Wt + (size_t)(col0 + srow) * K + sk;
    const __bf16* gB1 = gB0 + (size_t)64 * K;
    __bf16* lA0 = As + (size_t)c0 * 8;
    __bf16* lA1 = As + (size_t)(c0 + 256) * 8;
    __bf16* lB0 = Bs + (size_t)c0 * 8;
    __bf16* lB1 = Bs + (size_t)(c0 + 256) * 8;

    const int wr = w >> 1, wc = w & 1;
    const __bf16* rA = As + wr * 2048 + lane * 8;
    const __bf16* rB = Bs + wc * 2048 + lane * 8;

    v4f acc[4][4] = {};
    for (int k0 = 0; k0 < K; k0 += 32) {
        __builtin_amdgcn_global_load_lds(GAS(gA0), LAS(lA0), 16, 0, 0);
        __builtin_amdgcn_global_load_lds(GAS(gA1), LAS(lA1), 16, 0, 0);
        __builtin_amdgcn_global_load_lds(GAS(gB0), LAS(lB0), 16, 0, 0);
        __builtin_amdgcn_global_load_lds(GAS(gB1), LAS(lB1), 16, 0, 0);
        gA0 += 32; gA1 += 32; gB0 += 32; gB1 += 32;
        __syncthreads();
        v8bf af[4], bfr[4];
        #pragma unroll
        for (int i = 0; i < 4; ++i) af[i]  = *(const v8bf*)(rA + i * 512);
        #pragma unroll
        for (int j = 0; j < 4; ++j) bfr[j] = *(const v8bf*)(rB + j * 512);
        #pragma unroll
        for (int i = 0; i < 4; ++i)
            #pragma unroll
            for (int j = 0; j < 4; ++j)
                acc[i][j] = __builtin_amdgcn_mfma_f32_16x16x32_bf16(af[i], bfr[j], acc[i][j], 0, 0, 0);
        __syncthreads();
    }

    const int er = (lane >> 4) * 4;
    const int ec = lane & 15;
    #pragma unroll
    for (int j = 0; j < 4; ++j) {
        const int col = col0 + wc * 64 + j * 16 + ec;
        const float bval = bias[col];
        #pragma unroll
        for (int i = 0; i < 4; ++i) {
            #pragma unroll
            for (int rr = 0; rr < 4; ++rr) {
                const int row = row0 + wr * 64 + i * 16 + er + rr;
                float vv = acc[i][j][rr] + bval;
                if (DOGELU) vv = 0.5f * vv * (1.f + erff(vv * 0.70710678118f));
                if (DORES)  vv += res[(size_t)row * N + col];
                if (OUTBF16) ((__bf16*)Cout)[(size_t)row * N + col] = (__bf16)vv;
                else         ((float*) Cout)[(size_t)row * N + col] = vv;
            }
        }
    }
}

// ---------------- MFMA flash attention ----------------
// Block = 64 q-rows of one (b,h); 4 waves x 16 rows. K-tiles of 64 keys.
// QK^T: A=Q frag (regs, m=lane&15 -> q-row), B=K frag (n=lane&15 -> key).
// S in C-layout (col=lane&15=key, row=quad*4+reg=q-row); online softmax with
// row stats per reg (16-lane shfl reductions stay inside the quad group).
// P -> per-wave LDS (bf16, swizzled) -> A-layout frags; PV with Vt (dim-major,
// transposed+swizzled at staging via packed key-pair uint writes).
__global__ __launch_bounds__(256) void attn_mfma(const __bf16* __restrict__ qkv,
                                                 __bf16* __restrict__ y) {
    __shared__ __align__(16) __bf16 Qs[4096];
    __shared__ __align__(16) __bf16 Ks[4096];
    __shared__ __align__(16) __bf16 Vt[4096];
    __shared__ __align__(16) __bf16 Ps[4][1024];

    const int tid  = threadIdx.x;
    const int w    = tid >> 6;
    const int lane = tid & 63;
    const int quad = lane >> 4;
    const int l4   = lane & 15;

    const int qt = 31 - (blockIdx.x & 31);       // big tiles first
    const int bh = blockIdx.x >> 5;
    const int b  = bh / H;
    const int h  = bh - b * H;
    const int q0 = qt * 64;

    const __bf16* base = qkv + (size_t)(b * T) * D3 + h * HD;

    // stage Q tile (rows q0..q0+63), swizzled
    {
        int c = tid;
        #pragma unroll
        for (int rep = 0; rep < 2; ++rep, c += 256) {
            int row = c >> 3, ch = c & 7;
            v8us v = *(const v8us*)(const void*)(base + (size_t)(q0 + row) * D3 + ch * 8);
            *(v8us*)(void*)(Qs + LIDX(row, ch)) = v;
        }
    }

    float m[4]  = {-INFINITY, -INFINITY, -INFINITY, -INFINITY};
    float ll[4] = {0.f, 0.f, 0.f, 0.f};
    v4f o[4] = {};
    v8bf qf[2];

    const int vkp = tid & 31;     // key pair
    const int vdc = tid >> 5;     // dim chunk (8 dims)
    const int nt = qt + 1;

    for (int kt = 0; kt < nt; ++kt) {
        const int k0 = kt * 64;
        // ---- stage K tile (natural rows, swizzled) ----
        {
            int c = tid;
            #pragma unroll
            for (int rep = 0; rep < 2; ++rep, c += 256) {
                int row = c >> 3, ch = c & 7;
                v8us v = *(const v8us*)(const void*)(base + (size_t)(k0 + row) * D3 + D + ch * 8);
                *(v8us*)(void*)(Ks + LIDX(row, ch)) = v;
            }
        }
        // ---- stage V transposed: Vt[dim][key], swizzled ----
        {
            const __bf16* vsrc = base + 2 * D + vdc * 8;
            v8us v0 = *(const v8us*)(const void*)(vsrc + (size_t)(k0 + 2 * vkp) * D3);
            v8us v1 = *(const v8us*)(const void*)(vsrc + (size_t)(k0 + 2 * vkp + 1) * D3);
            #pragma unroll
            for (int j = 0; j < 8; ++j) {
                int dim = vdc * 8 + j;
                int idx = dim * 64 + ((((vkp >> 2) ^ (dim & 7))) << 3) + ((vkp & 3) << 1);
                *(unsigned int*)(void*)(Vt + idx) =
                    ((unsigned int)v1[j] << 16) | (unsigned int)v0[j];
            }
        }
        __syncthreads();

        if (kt == 0) {
            qf[0] = *(const v8bf*)(Qs + LIDX(w * 16 + l4, quad));
            qf[1] = *(const v8bf*)(Qs + LIDX(w * 16 + l4, 4 + quad));
        }

        // ---- S = Q K^T ----
        v4f s[4] = {};
        #pragma unroll
        for (int kh = 0; kh < 2; ++kh) {
            #pragma unroll
            for (int jb = 0; jb < 4; ++jb) {
                v8bf bk = *(const v8bf*)(Ks + LIDX(jb * 16 + l4, kh * 4 + quad));
                s[jb] = __builtin_amdgcn_mfma_f32_16x16x32_bf16(qf[kh], bk, s[jb], 0, 0, 0);
            }
        }

        // ---- online softmax (per q-row stats, rows live in quad groups) ----
        float p[4][4];
        #pragma unroll
        for (int r = 0; r < 4; ++r) {
            const int qrow = q0 + w * 16 + quad * 4 + r;
            float svv[4];
            float mr = m[r];
            #pragma unroll
            for (int jb = 0; jb < 4; ++jb) {
                float sv = s[jb][r] * 0.125f;
                if (k0 + jb * 16 + l4 > qrow) sv = -INFINITY;
                svv[jb] = sv;
                mr = fmaxf(mr, sv);
            }
            #pragma unroll
            for (int off = 1; off < 16; off <<= 1) mr = fmaxf(mr, __shfl_xor(mr, off));
            const float alpha = __expf(m[r] - mr);
            float ps = 0.f;
            #pragma unroll
            for (int jb = 0; jb < 4; ++jb) {
                float pv = __expf(svv[jb] - mr);
                p[jb][r] = pv;
                ps += pv;
            }
            #pragma unroll
            for (int off = 1; off < 16; off <<= 1) ps += __shfl_xor(ps, off);
            ll[r] = ll[r] * alpha + ps;
            m[r] = mr;
            #pragma unroll
            for (int db = 0; db < 4; ++db) o[db][r] *= alpha;
        }

        // ---- P (C-layout) -> per-wave LDS, bf16, swizzled ----
        #pragma unroll
        for (int jb = 0; jb < 4; ++jb) {
            #pragma unroll
            for (int r = 0; r < 4; ++r) {
                const int prow = quad * 4 + r;
                const int pidx = prow * 64 + ((((jb * 2 + (l4 >> 3)) ^ (prow & 7))) << 3) + (l4 & 7);
                Ps[w][pidx] = (__bf16)p[jb][r];
            }
        }
        // (same-wave LDS write->read: compiler inserts lgkmcnt wait; no barrier)

        // ---- O += P V ----
        #pragma unroll
        for (int kh = 0; kh < 2; ++kh) {
            v8bf ap = *(const v8bf*)(&Ps[w][LIDX(l4, kh * 4 + quad)]);
            #pragma unroll
            for (int db = 0; db < 4; ++db) {
                v8bf bv = *(const v8bf*)(Vt + LIDX(db * 16 + l4, kh * 4 + quad));
                o[db] = __builtin_amdgcn_mfma_f32_16x16x32_bf16(ap, bv, o[db], 0, 0, 0);
            }
        }
        __syncthreads();
    }

    // ---- epilogue: O / l -> y ----
    #pragma unroll
    for (int db = 0; db < 4; ++db) {
        #pragma unroll
        for (int r = 0; r < 4; ++r) {
            const int q = q0 + w * 16 + quad * 4 + r;
            y[(size_t)(b * T + q) * D + h * HD + db * 16 + l4] = (__bf16)(o[db][r] / ll[r]);
        }
    }
}

// ---------------- lm head: out[b,v] = dot(xf[b,:], wte[v,:]) --------------
__global__ __launch_bounds__(256) void logits_kernel(const __bf16* __restrict__ xf,
                                                     const float* __restrict__ wte,
                                                     float* __restrict__ out) {
    int wave = threadIdx.x >> 6;
    int lane = threadIdx.x & 63;
    int gid = blockIdx.x * 4 + wave;
    if (gid >= B * V) return;
    int b = gid / V;
    int v = gid - b * V;
    const float* wr = wte + (size_t)v * D;
    const __bf16* xr = xf + b * D;
    float s = 0.f;
    #pragma unroll
    for (int j = 0; j < 12; ++j)
        s = fmaf(wr[lane + 64 * j], (float)xr[lane + 64 * j], s);
    #pragma unroll
    for (int off = 32; off; off >>= 1) s += __shfl_xor(s, off);
    if (lane == 0) out[gid] = s;
}

extern "C" void kernel_launch(void* const* d_in, const int* in_sizes, int n_in,
                              void* d_out, int out_size, void* d_ws, size_t ws_size,
                              hipStream_t stream) {
    const int*   idx    = (const int*)  d_in[0];
    const float* wte    = (const float*)d_in[1];
    const float* wpe    = (const float*)d_in[2];
    const float* ln1_w  = (const float*)d_in[3];
    const float* ln1_b  = (const float*)d_in[4];
    const float* attn_w = (const float*)d_in[5];
    const float* attn_b = (const float*)d_in[6];
    const float* proj_w = (const float*)d_in[7];
    const float* proj_b = (const float*)d_in[8];
    const float* ln2_w  = (const float*)d_in[9];
    const float* ln2_b  = (const float*)d_in[10];
    const float* fc_w   = (const float*)d_in[11];
    const float* fc_b   = (const float*)d_in[12];
    const float* fcp_w  = (const float*)d_in[13];
    const float* fcp_b  = (const float*)d_in[14];
    const float* lnf_w  = (const float*)d_in[15];
    const float* lnf_b  = (const float*)d_in[16];
    float* out = (float*)d_out;

    // workspace carve; qkv (bf16) and gelu-out (bf16) share one region
    // (qkv dead once attention finishes, gelu-out written after)
    char* ws = (char*)d_ws;
    float*  x    = (float*)ws;  ws += (size_t)NTOK * D  * 4;   // residual stream fp32
    __bf16* qkvb = (__bf16*)ws;                                 // [NTOK,3D] bf16
    __bf16* gb   = (__bf16*)ws; ws += (size_t)NTOK * D4 * 2;   // [NTOK,4D] bf16 (alias)
    __bf16* hb   = (__bf16*)ws; ws += (size_t)NTOK * D  * 2;   // ln out
    __bf16* yb   = (__bf16*)ws; ws += (size_t)NTOK * D  * 2;   // attn out
    __bf16* awt  = (__bf16*)ws; ws += (size_t)D3 * D   * 2;    // attn_w^T
    __bf16* pwt  = (__bf16*)ws; ws += (size_t)D  * D   * 2;    // proj_w^T
    __bf16* fwt  = (__bf16*)ws; ws += (size_t)D4 * D   * 2;    // fc_w^T
    __bf16* fpwt = (__bf16*)ws; ws += (size_t)D  * D4  * 2;    // fcp_w^T
    __bf16* xf   = (__bf16*)ws; ws += (size_t)B * D    * 2;

    embed_kernel<<<(NTOK * D + 255) / 256, 256, 0, stream>>>(idx, wte, wpe, x);

    for (int l = 0; l < L; ++l) {
        const float* l1w = ln1_w + l * D;
        const float* l1b = ln1_b + l * D;
        const float* aw  = attn_w + (size_t)l * D * D3;
        const float* ab  = attn_b + l * D3;
        const float* pw  = proj_w + (size_t)l * D * D;
        const float* pb  = proj_b + l * D;
        const float* l2w = ln2_w + l * D;
        const float* l2b = ln2_b + l * D;
        const float* fw  = fc_w + (size_t)l * D * D4;
        const float* fb  = fc_b + l * D4;
        const float* fpw = fcp_w + (size_t)l * D4 * D;
        const float* fpb = fcp_b + l * D;

        convw_kernel<<<dim3(D3 / 32, D / 32),  256, 0, stream>>>(aw,  awt,  D,  D3);
        convw_kernel<<<dim3(D / 32,  D / 32),  256, 0, stream>>>(pw,  pwt,  D,  D);
        convw_kernel<<<dim3(D4 / 32, D / 32),  256, 0, stream>>>(fw,  fwt,  D,  D4);
        convw_kernel<<<dim3(D / 32,  D4 / 32), 256, 0, stream>>>(fpw, fpwt, D4, D);

        // h = ln1(x)
        ln_kernel<<<NTOK, 256, 0, stream>>>(x, l1w, l1b, hb, 1, 0);
        // qkv = h @ aw + ab  [bf16]
        gemm_bt<true, false, false><<<dim3(D3 / 128, NTOK / 128), 256, 0, stream>>>(
            hb, awt, ab, nullptr, qkvb, D3, D);
        // y = flash-attention(qkv)  [bf16]
        attn_mfma<<<B * H * (T / 64), 256, 0, stream>>>(qkvb, yb);
        // x = x + y @ pw + pb
        gemm_bt<false, false, true><<<dim3(D / 128, NTOK / 128), 256, 0, stream>>>(
            yb, pwt, pb, x, x, D, D);
        // h = ln2(x)
        ln_kernel<<<NTOK, 256, 0, stream>>>(x, l2w, l2b, hb, 1, 0);
        // gb = gelu(h @ fw + fb)  [bf16]
        gemm_bt<true, true, false><<<dim3(D4 / 128, NTOK / 128), 256, 0, stream>>>(
            hb, fwt, fb, nullptr, gb, D4, D);
        // x = x + gb @ fpw + fpb
        gemm_bt<false, false, true><<<dim3(D / 128, NTOK / 128), 256, 0, stream>>>(
            gb, fpwt, fpb, x, x, D, D4);
    }

    ln_kernel<<<B, 256, 0, stream>>>(x, lnf_w, lnf_b, xf, T, T - 1);
    logits_kernel<<<(B * V + 3) / 4, 256, 0, stream>>>(xf, wte, out);
}

// Round 5
// 1588.874 us; speedup vs baseline: 13.6022x; 1.0322x over previous
//
#include <hip/hip_runtime.h>
#include <math.h>

#define V 50257
#define B 2
#define T 2048
#define D 768
#define H 12
#define HD 64
#define L 4
#define D3 (3*D)
#define D4 (4*D)
#define NTOK (B*T)          // 4096
#define EPS 1e-5f

typedef __bf16 v8bf __attribute__((ext_vector_type(8)));
typedef unsigned short v8us __attribute__((ext_vector_type(8)));
typedef float  v4f  __attribute__((ext_vector_type(4)));

#define GAS(p) ((const __attribute__((address_space(1))) void*)(p))
#define LAS(p) ((__attribute__((address_space(3))) void*)(p))

// swizzled LDS tile addressing: 64-elem (128B) rows, 16B chunks, chunk ^= row&7.
#define LIDX(row, chunk) ((row)*64 + ((((chunk) ^ ((row)&7)))<<3))

// ---------------- embedding ----------------
__global__ __launch_bounds__(256) void embed_kernel(const int* __restrict__ idx,
                                                    const float* __restrict__ wte,
                                                    const float* __restrict__ wpe,
                                                    float* __restrict__ x) {
    int i = blockIdx.x * 256 + threadIdx.x;
    if (i >= NTOK * D) return;
    int pos = i / D;
    int d   = i - pos * D;
    int t   = pos & (T - 1);
    int tok = idx[pos];
    x[i] = wte[tok * D + d] + wpe[t * D + d];
}

// ---------------- layernorm: fp32 in, bf16 out ----------------
__global__ __launch_bounds__(256) void ln_kernel(const float* __restrict__ X,
                                                 const float* __restrict__ w,
                                                 const float* __restrict__ b,
                                                 __bf16* __restrict__ Y,
                                                 int src_mul, int src_off) {
    int srow = blockIdx.x * src_mul + src_off;
    const float* xr = X + (size_t)srow * D;
    float v[3];
    float s = 0.f, s2 = 0.f;
    #pragma unroll
    for (int j = 0; j < 3; ++j) {
        v[j] = xr[threadIdx.x + 256 * j];
        s += v[j];
        s2 += v[j] * v[j];
    }
    #pragma unroll
    for (int off = 32; off; off >>= 1) {
        s  += __shfl_xor(s, off);
        s2 += __shfl_xor(s2, off);
    }
    __shared__ float ss[4], ss2[4];
    int wave = threadIdx.x >> 6, lane = threadIdx.x & 63;
    if (lane == 0) { ss[wave] = s; ss2[wave] = s2; }
    __syncthreads();
    s  = ss[0] + ss[1] + ss[2] + ss[3];
    s2 = ss2[0] + ss2[1] + ss2[2] + ss2[3];
    float mu  = s * (1.f / D);
    float var = s2 * (1.f / D) - mu * mu;
    float rs  = rsqrtf(var + EPS);
    __bf16* yr = Y + (size_t)blockIdx.x * D;
    #pragma unroll
    for (int j = 0; j < 3; ++j) {
        int c = threadIdx.x + 256 * j;
        yr[c] = (__bf16)((v[j] - mu) * rs * w[c] + b[c]);
    }
}

// ------- per-layer fused weight convert+transpose (4 matrices, 1 dispatch) ----
// block-range decode: aw 72x24=1728, pw 24x24=576, fw 96x24=2304, fpw 24x96=2304
__global__ __launch_bounds__(256) void convw4_kernel(
        const float* __restrict__ aw,  const float* __restrict__ pw,
        const float* __restrict__ fw,  const float* __restrict__ fpw,
        __bf16* __restrict__ awt, __bf16* __restrict__ pwt,
        __bf16* __restrict__ fwt, __bf16* __restrict__ fpwt) {
    int bid = blockIdx.x;
    const float* W; __bf16* Wt; int K, N, bx, by;
    if (bid < 1728)      {             W = aw;  Wt = awt;  K = D;  N = D3; bx = bid % 72; by = bid / 72; }
    else if (bid < 2304) { bid -= 1728; W = pw;  Wt = pwt;  K = D;  N = D;  bx = bid % 24; by = bid / 24; }
    else if (bid < 4608) { bid -= 2304; W = fw;  Wt = fwt;  K = D;  N = D4; bx = bid % 96; by = bid / 96; }
    else                 { bid -= 4608; W = fpw; Wt = fpwt; K = D4; N = D;  bx = bid % 24; by = bid / 24; }
    __shared__ float t[32][33];
    const int n0 = bx * 32, k0 = by * 32;
    const int tx = threadIdx.x & 31, ty = threadIdx.x >> 5;
    #pragma unroll
    for (int p = 0; p < 4; ++p)
        t[ty + 8 * p][tx] = W[(size_t)(k0 + ty + 8 * p) * N + n0 + tx];
    __syncthreads();
    #pragma unroll
    for (int p = 0; p < 4; ++p)
        Wt[(size_t)(n0 + ty + 8 * p) * K + k0 + tx] = (__bf16)t[tx][ty + 8 * p];
}

// ---------------- bf16 MFMA GEMM 128x128 (B^T form) ----------------
template<bool OUTBF16, bool DOGELU, bool DORES>
__global__ __launch_bounds__(256) void gemm_bt(const __bf16* __restrict__ A,
                                               const __bf16* __restrict__ Wt,
                                               const float* __restrict__ bias,
                                               const float* __restrict__ res,
                                               void* __restrict__ Cout,
                                               int N, int K) {
    __shared__ __align__(16) __bf16 As[4096];
    __shared__ __align__(16) __bf16 Bs[4096];
    const int tid  = threadIdx.x;
    const int w    = tid >> 6;
    const int lane = tid & 63;
    const int row0 = blockIdx.y * 128;
    const int col0 = blockIdx.x * 128;

    const int c0   = w * 64 + lane;
    const int srow = ((c0 >> 6) & 3) * 16 + (c0 & 15);
    const int sk   = ((c0 >> 4) & 3) * 8;
    const __bf16* gA0 = A  + (size_t)(row0 + srow) * K + sk;
    const __bf16* gA1 = gA0 + (size_t)64 * K;
    const __bf16* gB0 = Wt + (size_t)(col0 + srow) * K + sk;
    const __bf16* gB1 = gB0 + (size_t)64 * K;
    __bf16* lA0 = As + (size_t)c0 * 8;
    __bf16* lA1 = As + (size_t)(c0 + 256) * 8;
    __bf16* lB0 = Bs + (size_t)c0 * 8;
    __bf16* lB1 = Bs + (size_t)(c0 + 256) * 8;

    const int wr = w >> 1, wc = w & 1;
    const __bf16* rA = As + wr * 2048 + lane * 8;
    const __bf16* rB = Bs + wc * 2048 + lane * 8;

    v4f acc[4][4] = {};
    for (int k0 = 0; k0 < K; k0 += 32) {
        __builtin_amdgcn_global_load_lds(GAS(gA0), LAS(lA0), 16, 0, 0);
        __builtin_amdgcn_global_load_lds(GAS(gA1), LAS(lA1), 16, 0, 0);
        __builtin_amdgcn_global_load_lds(GAS(gB0), LAS(lB0), 16, 0, 0);
        __builtin_amdgcn_global_load_lds(GAS(gB1), LAS(lB1), 16, 0, 0);
        gA0 += 32; gA1 += 32; gB0 += 32; gB1 += 32;
        __syncthreads();
        v8bf af[4], bfr[4];
        #pragma unroll
        for (int i = 0; i < 4; ++i) af[i]  = *(const v8bf*)(rA + i * 512);
        #pragma unroll
        for (int j = 0; j < 4; ++j) bfr[j] = *(const v8bf*)(rB + j * 512);
        #pragma unroll
        for (int i = 0; i < 4; ++i)
            #pragma unroll
            for (int j = 0; j < 4; ++j)
                acc[i][j] = __builtin_amdgcn_mfma_f32_16x16x32_bf16(af[i], bfr[j], acc[i][j], 0, 0, 0);
        __syncthreads();
    }

    const int er = (lane >> 4) * 4;
    const int ec = lane & 15;
    #pragma unroll
    for (int j = 0; j < 4; ++j) {
        const int col = col0 + wc * 64 + j * 16 + ec;
        const float bval = bias[col];
        #pragma unroll
        for (int i = 0; i < 4; ++i) {
            #pragma unroll
            for (int rr = 0; rr < 4; ++rr) {
                const int row = row0 + wr * 64 + i * 16 + er + rr;
                float vv = acc[i][j][rr] + bval;
                if (DOGELU) vv = 0.5f * vv * (1.f + erff(vv * 0.70710678118f));
                if (DORES)  vv += res[(size_t)row * N + col];
                if (OUTBF16) ((__bf16*)Cout)[(size_t)row * N + col] = (__bf16)vv;
                else         ((float*) Cout)[(size_t)row * N + col] = vv;
            }
        }
    }
}

// ---------------- bf16 MFMA GEMM 128x64 (for N=768: 2x the blocks) ----------
template<bool OUTBF16, bool DOGELU, bool DORES>
__global__ __launch_bounds__(256) void gemm_bt64(const __bf16* __restrict__ A,
                                                 const __bf16* __restrict__ Wt,
                                                 const float* __restrict__ bias,
                                                 const float* __restrict__ res,
                                                 void* __restrict__ Cout,
                                                 int N, int K) {
    __shared__ __align__(16) __bf16 As[4096];
    __shared__ __align__(16) __bf16 Bs[2048];
    const int tid  = threadIdx.x;
    const int w    = tid >> 6;
    const int lane = tid & 63;
    const int row0 = blockIdx.y * 128;
    const int col0 = blockIdx.x * 64;

    const int c0   = w * 64 + lane;
    const int srow = ((c0 >> 6) & 3) * 16 + (c0 & 15);
    const int sk   = ((c0 >> 4) & 3) * 8;
    const __bf16* gA0 = A  + (size_t)(row0 + srow) * K + sk;
    const __bf16* gA1 = gA0 + (size_t)64 * K;
    const __bf16* gB0 = Wt + (size_t)(col0 + srow) * K + sk;   // 256 chunks: rows 0..63
    __bf16* lA0 = As + (size_t)c0 * 8;
    __bf16* lA1 = As + (size_t)(c0 + 256) * 8;
    __bf16* lB0 = Bs + (size_t)c0 * 8;

    const int wr = w >> 1, wc = w & 1;
    const __bf16* rA = As + wr * 2048 + lane * 8;
    const __bf16* rB = Bs + wc * 1024 + lane * 8;

    v4f acc[4][2] = {};
    for (int k0 = 0; k0 < K; k0 += 32) {
        __builtin_amdgcn_global_load_lds(GAS(gA0), LAS(lA0), 16, 0, 0);
        __builtin_amdgcn_global_load_lds(GAS(gA1), LAS(lA1), 16, 0, 0);
        __builtin_amdgcn_global_load_lds(GAS(gB0), LAS(lB0), 16, 0, 0);
        gA0 += 32; gA1 += 32; gB0 += 32;
        __syncthreads();
        v8bf af[4], bfr[2];
        #pragma unroll
        for (int i = 0; i < 4; ++i) af[i]  = *(const v8bf*)(rA + i * 512);
        #pragma unroll
        for (int j = 0; j < 2; ++j) bfr[j] = *(const v8bf*)(rB + j * 512);
        #pragma unroll
        for (int i = 0; i < 4; ++i)
            #pragma unroll
            for (int j = 0; j < 2; ++j)
                acc[i][j] = __builtin_amdgcn_mfma_f32_16x16x32_bf16(af[i], bfr[j], acc[i][j], 0, 0, 0);
        __syncthreads();
    }

    const int er = (lane >> 4) * 4;
    const int ec = lane & 15;
    #pragma unroll
    for (int j = 0; j < 2; ++j) {
        const int col = col0 + wc * 32 + j * 16 + ec;
        const float bval = bias[col];
        #pragma unroll
        for (int i = 0; i < 4; ++i) {
            #pragma unroll
            for (int rr = 0; rr < 4; ++rr) {
                const int row = row0 + wr * 64 + i * 16 + er + rr;
                float vv = acc[i][j][rr] + bval;
                if (DOGELU) vv = 0.5f * vv * (1.f + erff(vv * 0.70710678118f));
                if (DORES)  vv += res[(size_t)row * N + col];
                if (OUTBF16) ((__bf16*)Cout)[(size_t)row * N + col] = (__bf16)vv;
                else         ((float*) Cout)[(size_t)row * N + col] = vv;
            }
        }
    }
}

// ---------------- MFMA flash attention: 128 q-rows/block, K/V prefetch -------
__global__ __launch_bounds__(256) void attn_mfma(const __bf16* __restrict__ qkv,
                                                 __bf16* __restrict__ y) {
    __shared__ __align__(16) __bf16 Qs[8192];
    __shared__ __align__(16) __bf16 Ks[4096];
    __shared__ __align__(16) __bf16 Vt[4096];
    __shared__ __align__(16) __bf16 Ps[4][1024];

    const int tid  = threadIdx.x;
    const int w    = tid >> 6;
    const int lane = tid & 63;
    const int quad = lane >> 4;
    const int l4   = lane & 15;

    const int qt = 15 - (blockIdx.x & 15);       // big tiles first
    const int bh = blockIdx.x >> 4;
    const int b  = bh / H;
    const int h  = bh - b * H;
    const int q0 = qt * 128;

    const __bf16* base = qkv + (size_t)(b * T) * D3 + h * HD;

    // stage Q tile (128 rows), swizzled
    {
        int c = tid;
        #pragma unroll
        for (int rep = 0; rep < 4; ++rep, c += 256) {
            int row = c >> 3, ch = c & 7;
            v8us v = *(const v8us*)(const void*)(base + (size_t)(q0 + row) * D3 + ch * 8);
            *(v8us*)(void*)(Qs + LIDX(row, ch)) = v;
        }
    }

    const int krow = tid >> 3, kch = tid & 7;
    const int vkp = tid & 31, vdc = tid >> 5;
    const __bf16* kp0 = base + D     + (size_t)krow * D3 + kch * 8;
    const __bf16* kp1 = kp0 + (size_t)32 * D3;
    const __bf16* vp0 = base + 2 * D + (size_t)(2 * vkp) * D3 + vdc * 8;
    const __bf16* vp1 = vp0 + D3;

    v8us kr0 = *(const v8us*)(const void*)kp0;
    v8us kr1 = *(const v8us*)(const void*)kp1;
    v8us vr0 = *(const v8us*)(const void*)vp0;
    v8us vr1 = *(const v8us*)(const void*)vp1;

    float m[8], ll[8];
    #pragma unroll
    for (int i = 0; i < 8; ++i) { m[i] = -INFINITY; ll[i] = 0.f; }
    v4f o[8] = {};
    v8bf qf[2][2];

    const int nt = 2 * qt + 2;
    const size_t adv = (size_t)64 * D3;

    for (int kt = 0; kt < nt; ++kt) {
        const int k0 = kt * 64;
        // ---- write prefetched K tile (natural rows, swizzled) ----
        *(v8us*)(void*)(Ks + LIDX(krow, kch))      = kr0;
        *(v8us*)(void*)(Ks + LIDX(krow + 32, kch)) = kr1;
        // ---- write prefetched V transposed: Vt[dim][key], swizzled ----
        #pragma unroll
        for (int j = 0; j < 8; ++j) {
            int dim = vdc * 8 + j;
            int idx = dim * 64 + ((((vkp >> 2) ^ (dim & 7))) << 3) + ((vkp & 3) << 1);
            *(unsigned int*)(void*)(Vt + idx) =
                ((unsigned int)vr1[j] << 16) | (unsigned int)vr0[j];
        }
        __syncthreads();

        if (kt == 0) {
            #pragma unroll
            for (int rs = 0; rs < 2; ++rs)
                #pragma unroll
                for (int kh = 0; kh < 2; ++kh)
                    qf[rs][kh] = *(const v8bf*)(Qs + LIDX(w * 32 + rs * 16 + l4, kh * 4 + quad));
        }
        // ---- issue next tile's global loads (latency hidden by compute) ----
        if (kt + 1 < nt) {
            kp0 += adv; kp1 += adv; vp0 += adv; vp1 += adv;
            kr0 = *(const v8us*)(const void*)kp0;
            kr1 = *(const v8us*)(const void*)kp1;
            vr0 = *(const v8us*)(const void*)vp0;
            vr1 = *(const v8us*)(const void*)vp1;
        }

        #pragma unroll
        for (int rs = 0; rs < 2; ++rs) {
            // ---- S = Q K^T ----
            v4f s[4] = {};
            #pragma unroll
            for (int kh = 0; kh < 2; ++kh) {
                #pragma unroll
                for (int jb = 0; jb < 4; ++jb) {
                    v8bf bk = *(const v8bf*)(Ks + LIDX(jb * 16 + l4, kh * 4 + quad));
                    s[jb] = __builtin_amdgcn_mfma_f32_16x16x32_bf16(qf[rs][kh], bk, s[jb], 0, 0, 0);
                }
            }
            // ---- online softmax ----
            float p[4][4];
            #pragma unroll
            for (int r = 0; r < 4; ++r) {
                const int ridx = rs * 4 + r;
                const int qrow = q0 + w * 32 + rs * 16 + quad * 4 + r;
                float svv[4];
                float mr = m[ridx];
                #pragma unroll
                for (int jb = 0; jb < 4; ++jb) {
                    float sv = s[jb][r] * 0.125f;
                    if (k0 + jb * 16 + l4 > qrow) sv = -INFINITY;
                    svv[jb] = sv;
                    mr = fmaxf(mr, sv);
                }
                #pragma unroll
                for (int off = 1; off < 16; off <<= 1) mr = fmaxf(mr, __shfl_xor(mr, off));
                const float alpha = __expf(m[ridx] - mr);
                float ps = 0.f;
                #pragma unroll
                for (int jb = 0; jb < 4; ++jb) {
                    float pv = __expf(svv[jb] - mr);
                    p[jb][r] = pv;
                    ps += pv;
                }
                #pragma unroll
                for (int off = 1; off < 16; off <<= 1) ps += __shfl_xor(ps, off);
                ll[ridx] = ll[ridx] * alpha + ps;
                m[ridx] = mr;
                #pragma unroll
                for (int db = 0; db < 4; ++db) o[rs * 4 + db][r] *= alpha;
            }
            // ---- P (C-layout) -> per-wave LDS, bf16, swizzled ----
            #pragma unroll
            for (int jb = 0; jb < 4; ++jb) {
                #pragma unroll
                for (int r = 0; r < 4; ++r) {
                    const int prow = quad * 4 + r;
                    const int pidx = prow * 64 + ((((jb * 2 + (l4 >> 3)) ^ (prow & 7))) << 3) + (l4 & 7);
                    Ps[w][pidx] = (__bf16)p[jb][r];
                }
            }
            // ---- O += P V ----
            #pragma unroll
            for (int kh = 0; kh < 2; ++kh) {
                v8bf ap = *(const v8bf*)(&Ps[w][LIDX(l4, kh * 4 + quad)]);
                #pragma unroll
                for (int db = 0; db < 4; ++db) {
                    v8bf bv = *(const v8bf*)(Vt + LIDX(db * 16 + l4, kh * 4 + quad));
                    o[rs * 4 + db] = __builtin_amdgcn_mfma_f32_16x16x32_bf16(ap, bv, o[rs * 4 + db], 0, 0, 0);
                }
            }
        }
        __syncthreads();
    }

    // ---- epilogue ----
    #pragma unroll
    for (int rs = 0; rs < 2; ++rs)
        #pragma unroll
        for (int db = 0; db < 4; ++db)
            #pragma unroll
            for (int r = 0; r < 4; ++r) {
                const int q = q0 + w * 32 + rs * 16 + quad * 4 + r;
                y[(size_t)(b * T + q) * D + h * HD + db * 16 + l4] =
                    (__bf16)(o[rs * 4 + db][r] / ll[rs * 4 + r]);
            }
}

// ---------------- lm head ----------------
__global__ __launch_bounds__(256) void logits_kernel(const __bf16* __restrict__ xf,
                                                     const float* __restrict__ wte,
                                                     float* __restrict__ out) {
    int wave = threadIdx.x >> 6;
    int lane = threadIdx.x & 63;
    int gid = blockIdx.x * 4 + wave;
    if (gid >= B * V) return;
    int b = gid / V;
    int v = gid - b * V;
    const float* wr = wte + (size_t)v * D;
    const __bf16* xr = xf + b * D;
    float s = 0.f;
    #pragma unroll
    for (int j = 0; j < 12; ++j)
        s = fmaf(wr[lane + 64 * j], (float)xr[lane + 64 * j], s);
    #pragma unroll
    for (int off = 32; off; off >>= 1) s += __shfl_xor(s, off);
    if (lane == 0) out[gid] = s;
}

extern "C" void kernel_launch(void* const* d_in, const int* in_sizes, int n_in,
                              void* d_out, int out_size, void* d_ws, size_t ws_size,
                              hipStream_t stream) {
    const int*   idx    = (const int*)  d_in[0];
    const float* wte    = (const float*)d_in[1];
    const float* wpe    = (const float*)d_in[2];
    const float* ln1_w  = (const float*)d_in[3];
    const float* ln1_b  = (const float*)d_in[4];
    const float* attn_w = (const float*)d_in[5];
    const float* attn_b = (const float*)d_in[6];
    const float* proj_w = (const float*)d_in[7];
    const float* proj_b = (const float*)d_in[8];
    const float* ln2_w  = (const float*)d_in[9];
    const float* ln2_b  = (const float*)d_in[10];
    const float* fc_w   = (const float*)d_in[11];
    const float* fc_b   = (const float*)d_in[12];
    const float* fcp_w  = (const float*)d_in[13];
    const float* fcp_b  = (const float*)d_in[14];
    const float* lnf_w  = (const float*)d_in[15];
    const float* lnf_b  = (const float*)d_in[16];
    float* out = (float*)d_out;

    char* ws = (char*)d_ws;
    float*  x    = (float*)ws;  ws += (size_t)NTOK * D  * 4;   // residual stream fp32
    __bf16* qkvb = (__bf16*)ws;                                 // [NTOK,3D] bf16
    __bf16* gb   = (__bf16*)ws; ws += (size_t)NTOK * D4 * 2;   // [NTOK,4D] bf16 (alias)
    __bf16* hb   = (__bf16*)ws; ws += (size_t)NTOK * D  * 2;   // ln out
    __bf16* yb   = (__bf16*)ws; ws += (size_t)NTOK * D  * 2;   // attn out
    __bf16* awt  = (__bf16*)ws; ws += (size_t)D3 * D   * 2;    // attn_w^T
    __bf16* pwt  = (__bf16*)ws; ws += (size_t)D  * D   * 2;    // proj_w^T
    __bf16* fwt  = (__bf16*)ws; ws += (size_t)D4 * D   * 2;    // fc_w^T
    __bf16* fpwt = (__bf16*)ws; ws += (size_t)D  * D4  * 2;    // fcp_w^T
    __bf16* xf   = (__bf16*)ws; ws += (size_t)B * D    * 2;

    embed_kernel<<<(NTOK * D + 255) / 256, 256, 0, stream>>>(idx, wte, wpe, x);

    for (int l = 0; l < L; ++l) {
        const float* l1w = ln1_w + l * D;
        const float* l1b = ln1_b + l * D;
        const float* aw  = attn_w + (size_t)l * D * D3;
        const float* ab  = attn_b + l * D3;
        const float* pw  = proj_w + (size_t)l * D * D;
        const float* pb  = proj_b + l * D;
        const float* l2w = ln2_w + l * D;
        const float* l2b = ln2_b + l * D;
        const float* fw  = fc_w + (size_t)l * D * D4;
        const float* fb  = fc_b + l * D4;
        const float* fpw = fcp_w + (size_t)l * D4 * D;
        const float* fpb = fcp_b + l * D;

        // all 4 weight transposes in one dispatch
        convw4_kernel<<<6912, 256, 0, stream>>>(aw, pw, fw, fpw, awt, pwt, fwt, fpwt);

        // h = ln1(x)
        ln_kernel<<<NTOK, 256, 0, stream>>>(x, l1w, l1b, hb, 1, 0);
        // qkv = h @ aw + ab  [bf16]
        gemm_bt<true, false, false><<<dim3(D3 / 128, NTOK / 128), 256, 0, stream>>>(
            hb, awt, ab, nullptr, qkvb, D3, D);
        // y = flash-attention(qkv)  [bf16]
        attn_mfma<<<B * H * (T / 128), 256, 0, stream>>>(qkvb, yb);
        // x = x + y @ pw + pb   (N=768 -> 128x64 tiles, 384 blocks)
        gemm_bt64<false, false, true><<<dim3(D / 64, NTOK / 128), 256, 0, stream>>>(
            yb, pwt, pb, x, x, D, D);
        // h = ln2(x)
        ln_kernel<<<NTOK, 256, 0, stream>>>(x, l2w, l2b, hb, 1, 0);
        // gb = gelu(h @ fw + fb)  [bf16]
        gemm_bt<true, true, false><<<dim3(D4 / 128, NTOK / 128), 256, 0, stream>>>(
            hb, fwt, fb, nullptr, gb, D4, D);
        // x = x + gb @ fpw + fpb  (N=768 -> 128x64 tiles)
        gemm_bt64<false, false, true><<<dim3(D / 64, NTOK / 128), 256, 0, stream>>>(
            gb, fpwt, fpb, x, x, D, D4);
    }

    ln_kernel<<<B, 256, 0, stream>>>(x, lnf_w, lnf_b, xf, T, T - 1);
    logits_kernel<<<(B * V + 3) / 4, 256, 0, stream>>>(xf, wte, out);
}